// Round 1
// baseline (247.276 us; speedup 1.0000x reference)
//
#include <hip/hip_runtime.h>
#include <math.h>

#define NB 64
#define NT 512
#define HID 8192
#define NC 64
#define NH 4
#define HD 16
#define GD 64
#define IN_DIM 128

// ---------------------------------------------------------------------------
// Kernel 1: temporal mean pooling.
// H [B, T, HID] fp32 -> ni [B, HID] where ni[b, c*128+f] = mean_t H[b,t,c*128+f]
// ---------------------------------------------------------------------------
__global__ __launch_bounds__(256) void pool_kernel(const float* __restrict__ H,
                                                   float* __restrict__ ni) {
    const int b = blockIdx.y;
    const int idx4 = blockIdx.x * 256 + threadIdx.x;   // 0..HID/4-1
    const float4* src = reinterpret_cast<const float4*>(H + (size_t)b * NT * HID) + idx4;
    float4 acc = make_float4(0.f, 0.f, 0.f, 0.f);
#pragma unroll 8
    for (int t = 0; t < NT; ++t) {
        float4 v = src[(size_t)t * (HID / 4)];
        acc.x += v.x; acc.y += v.y; acc.z += v.z; acc.w += v.w;
    }
    const float s = 1.0f / NT;
    acc.x *= s; acc.y *= s; acc.z *= s; acc.w *= s;
    reinterpret_cast<float4*>(ni + (size_t)b * HID)[idx4] = acc;
}

// ---------------------------------------------------------------------------
// Kernel 2: everything else. One block per batch, 256 threads.
// ---------------------------------------------------------------------------
__global__ __launch_bounds__(256) void gat_kernel(
    const float* __restrict__ ni_g,
    const float* __restrict__ W_embed,   // [GD, IN_DIM]
    const float* __restrict__ b_embed,   // [GD]
    const float* __restrict__ Wh_w,      // [NH, HD, GD]
    const float* __restrict__ a_w,       // [NH, 2*HD]
    const float* __restrict__ Wr,        // [IN_DIM, GD]
    const float* __restrict__ br,        // [IN_DIM]
    float* __restrict__ out_g,           // [B, IN_DIM]
    float* __restrict__ out_attn)        // [B, NH, C, C]
{
    __shared__ float sm_We[IN_DIM * GD];   // transposed: [f][g]   32KB
    __shared__ float sm_ni[NC * IN_DIM];   // [c][f]               32KB
    __shared__ float sm_nodes[NC * GD];    // [c][g], reused as n_prime [c][ho]  16KB
    __shared__ float sm_Ww[GD * GD];       // transposed: [g][ho]  16KB
    __shared__ float sm_Wh[NC * GD];       // [c][ho]              16KB
    __shared__ float sm_s1[NH * NC];
    __shared__ float sm_s2[NH * NC];
    __shared__ float sm_mean[GD];

    const int tid = threadIdx.x;
    const int b = blockIdx.x;

    // ---- stage weights (transposed for conflict-free inner loops) + pooled inputs
    for (int idx = tid; idx < IN_DIM * GD; idx += 256) {
        int g = idx >> 7, f = idx & 127;          // W_embed[g][f]
        sm_We[f * GD + g] = W_embed[idx];
    }
    for (int idx = tid; idx < NC * IN_DIM; idx += 256)
        sm_ni[idx] = ni_g[(size_t)b * HID + idx];
    for (int idx = tid; idx < GD * GD; idx += 256) {
        int ho = idx >> 6, g = idx & 63;          // Wh_w[ho][g]
        sm_Ww[g * GD + ho] = Wh_w[idx];
    }
    __syncthreads();

    // ---- nodes[c][g] = ni[c][:] . We[g][:] + b_embed[g]
    for (int out = tid; out < NC * GD; out += 256) {
        int c = out >> 6, g = out & 63;
        float acc = b_embed[g];
#pragma unroll 4
        for (int f = 0; f < IN_DIM; ++f)
            acc += sm_ni[c * IN_DIM + f] * sm_We[f * GD + g];
        sm_nodes[out] = acc;
    }
    __syncthreads();

    // ---- Wh[c][ho] = nodes[c][:] . Wh_w[ho][:]
    for (int out = tid; out < NC * GD; out += 256) {
        int c = out >> 6, ho = out & 63;
        float acc = 0.f;
#pragma unroll 4
        for (int g = 0; g < GD; ++g)
            acc += sm_nodes[c * GD + g] * sm_Ww[g * GD + ho];
        sm_Wh[out] = acc;
    }
    __syncthreads();

    // ---- s1/s2: one (h,c) per thread
    {
        int h = tid >> 6, c = tid & 63;
        float acc1 = 0.f, acc2 = 0.f;
#pragma unroll
        for (int o = 0; o < HD; ++o) {
            float w = sm_Wh[c * GD + h * HD + o];
            acc1 += w * a_w[h * 2 * HD + o];
            acc2 += w * a_w[h * 2 * HD + HD + o];
        }
        sm_s1[h * NC + c] = acc1;
        sm_s2[h * NC + c] = acc2;
    }
    __syncthreads();

    // ---- softmax attention + PV, one (h,i) per thread
    {
        int h = tid >> 6, i = tid & 63;
        float s1 = sm_s1[h * NC + i];
        const float* s2p = &sm_s2[h * NC];

        float m = -1e30f;
        for (int j = 0; j < NC; ++j) {
            float x = s1 + s2p[j];
            float e = x > 0.f ? x : 0.2f * x;
            m = fmaxf(m, e);
        }
        float sum = 0.f;
        for (int j = 0; j < NC; ++j) {
            float x = s1 + s2p[j];
            float e = x > 0.f ? x : 0.2f * x;
            sum += expf(e - m);
        }
        float inv = 1.0f / sum;

        float acc[HD];
#pragma unroll
        for (int o = 0; o < HD; ++o) acc[o] = 0.f;

        float* attn_row = out_attn + ((((size_t)b * NH + h) * NC + i) * NC);
        for (int j = 0; j < NC; ++j) {
            float x = s1 + s2p[j];
            float e = x > 0.f ? x : 0.2f * x;
            float p = expf(e - m) * inv;
            attn_row[j] = p;
            const float* whj = &sm_Wh[j * GD + h * HD];
#pragma unroll
            for (int o = 0; o < HD; ++o)
                acc[o] += p * whj[o];
        }

        // elu + scatter into n_prime (reuse sm_nodes; its readers are past the barrier)
        float* np_row = &sm_nodes[i * GD + h * HD];
#pragma unroll
        for (int o = 0; o < HD; ++o) {
            float v = acc[o];
            np_row[o] = v > 0.f ? v : expm1f(v);
        }
    }
    __syncthreads();

    // ---- mean over nodes
    if (tid < GD) {
        float s = 0.f;
        for (int c = 0; c < NC; ++c) s += sm_nodes[c * GD + tid];
        sm_mean[tid] = s * (1.0f / NC);
    }
    __syncthreads();

    // ---- readout: g[i] = relu(mean . Wr[i][:] + br[i])
    if (tid < IN_DIM) {
        float acc = br[tid];
#pragma unroll 4
        for (int g = 0; g < GD; ++g)
            acc += sm_mean[g] * Wr[tid * GD + g];
        out_g[(size_t)b * IN_DIM + tid] = fmaxf(acc, 0.f);
    }
}

extern "C" void kernel_launch(void* const* d_in, const int* in_sizes, int n_in,
                              void* d_out, int out_size, void* d_ws, size_t ws_size,
                              hipStream_t stream) {
    const float* H       = (const float*)d_in[0];
    const float* W_embed = (const float*)d_in[1];
    const float* b_embed = (const float*)d_in[2];
    const float* Wh_w    = (const float*)d_in[3];
    const float* a_w     = (const float*)d_in[4];
    const float* Wr      = (const float*)d_in[5];
    const float* br      = (const float*)d_in[6];
    float* out = (float*)d_out;
    float* ni  = (float*)d_ws;   // [B, HID] = 2 MB

    dim3 g1(HID / 4 / 256, NB);  // (8, 64)
    pool_kernel<<<g1, dim3(256), 0, stream>>>(H, ni);
    gat_kernel<<<dim3(NB), dim3(256), 0, stream>>>(ni, W_embed, b_embed, Wh_w, a_w,
                                                   Wr, br, out, out + NB * IN_DIM);
}

// Round 2
// 232.493 us; speedup vs baseline: 1.0636x; 1.0636x over previous
//
#include <hip/hip_runtime.h>
#include <math.h>

#define NB 64
#define NT 512
#define HID 8192
#define NC 64
#define NH 4
#define HD 16
#define GD 64
#define IN_DIM 128
#define TSPLIT 4

// ---------------------------------------------------------------------------
// Kernel 1: temporal partial-sum pooling.
// H [B, T, HID] -> ws[ts][b][HID] = sum over t in segment ts.
// grid (HID/4/256, B, TS), block 256. TS passed at runtime (4, or 1 fallback).
// ---------------------------------------------------------------------------
__global__ __launch_bounds__(256) void pool_kernel(const float* __restrict__ H,
                                                   float* __restrict__ part,
                                                   int ts_count) {
    const int b = blockIdx.y;
    const int ts = blockIdx.z;
    const int idx4 = blockIdx.x * 256 + threadIdx.x;   // 0..HID/4-1
    const int rows = NT / ts_count;
    const float4* src = reinterpret_cast<const float4*>(H + (size_t)b * NT * HID) +
                        (size_t)(ts * rows) * (HID / 4) + idx4;
    float4 acc = make_float4(0.f, 0.f, 0.f, 0.f);
#pragma unroll 8
    for (int t = 0; t < rows; ++t) {
        float4 v = src[(size_t)t * (HID / 4)];
        acc.x += v.x; acc.y += v.y; acc.z += v.z; acc.w += v.w;
    }
    reinterpret_cast<float4*>(part + ((size_t)ts * NB + b) * HID)[idx4] = acc;
}

// ---------------------------------------------------------------------------
// Kernel 2: everything else. One block per batch, 1024 threads (16 waves).
// ---------------------------------------------------------------------------
__global__ __launch_bounds__(1024) void gat_kernel(
    const float* __restrict__ part,      // [TS, B, HID] partial sums
    const float* __restrict__ W_embed,   // [GD, IN_DIM]
    const float* __restrict__ b_embed,   // [GD]
    const float* __restrict__ Wh_w,      // [NH, HD, GD]
    const float* __restrict__ a_w,       // [NH, 2*HD]
    const float* __restrict__ Wr,        // [IN_DIM, GD]
    const float* __restrict__ br,        // [IN_DIM]
    float* __restrict__ out_g,           // [B, IN_DIM]
    float* __restrict__ out_attn,        // [B, NH, C, C]
    int ts_count)
{
    __shared__ float sm_We[IN_DIM * GD];   // transposed: [f][g]   32KB
    __shared__ float sm_ni[NC * IN_DIM];   // [c][f]               32KB
    __shared__ float sm_nodes[NC * GD];    // [c][g], reused as n_prime  16KB
    __shared__ float sm_Ww[GD * GD];       // transposed: [g][ho]  16KB
    __shared__ float sm_Wh[NC * GD];       // [c][ho]              16KB
    __shared__ float sm_s1[NH * NC];
    __shared__ float sm_s2[NH * NC];
    __shared__ float sm_mean[GD];

    const int tid = threadIdx.x;
    const int b = blockIdx.x;

    // ---- stage weights (transposed) + fold pooled partial sums -> mean
    for (int idx = tid; idx < IN_DIM * GD; idx += 1024) {
        int g = idx >> 7, f = idx & 127;          // W_embed[g][f]
        sm_We[f * GD + g] = W_embed[idx];
    }
    for (int idx = tid; idx < NC * IN_DIM; idx += 1024) {
        float s = 0.f;
        for (int ts = 0; ts < ts_count; ++ts)
            s += part[((size_t)ts * NB + b) * HID + idx];
        sm_ni[idx] = s * (1.0f / NT);
    }
    for (int idx = tid; idx < GD * GD; idx += 1024) {
        int ho = idx >> 6, g = idx & 63;          // Wh_w[ho][g]
        sm_Ww[g * GD + ho] = Wh_w[idx];
    }
    __syncthreads();

    // ---- nodes[c][g] = ni[c][:] . We[:][g] + b_embed[g]
    for (int out = tid; out < NC * GD; out += 1024) {
        int c = out >> 6, g = out & 63;
        float acc = b_embed[g];
#pragma unroll 4
        for (int f = 0; f < IN_DIM; ++f)
            acc += sm_ni[c * IN_DIM + f] * sm_We[f * GD + g];
        sm_nodes[out] = acc;
    }
    __syncthreads();

    // ---- Wh[c][ho] = nodes[c][:] . Ww[:][ho]
    for (int out = tid; out < NC * GD; out += 1024) {
        int c = out >> 6, ho = out & 63;
        float acc = 0.f;
#pragma unroll 4
        for (int g = 0; g < GD; ++g)
            acc += sm_nodes[c * GD + g] * sm_Ww[g * GD + ho];
        sm_Wh[out] = acc;
    }
    __syncthreads();

    // ---- s1/s2: one (h,c) per thread
    if (tid < NH * NC) {
        int h = tid >> 6, c = tid & 63;
        float acc1 = 0.f, acc2 = 0.f;
#pragma unroll
        for (int o = 0; o < HD; ++o) {
            float w = sm_Wh[c * GD + h * HD + o];
            acc1 += w * a_w[h * 2 * HD + o];
            acc2 += w * a_w[h * 2 * HD + HD + o];
        }
        sm_s1[h * NC + c] = acc1;
        sm_s2[h * NC + c] = acc2;
    }
    __syncthreads();

    // ---- softmax attention + PV, one (h,i) per thread
    if (tid < NH * NC) {
        int h = tid >> 6, i = tid & 63;
        float s1 = sm_s1[h * NC + i];
        const float* s2p = &sm_s2[h * NC];

        float m = -1e30f;
        for (int j = 0; j < NC; ++j) {
            float x = s1 + s2p[j];
            float e = x > 0.f ? x : 0.2f * x;
            m = fmaxf(m, e);
        }
        float sum = 0.f;
        for (int j = 0; j < NC; ++j) {
            float x = s1 + s2p[j];
            float e = x > 0.f ? x : 0.2f * x;
            sum += expf(e - m);
        }
        float inv = 1.0f / sum;

        float acc[HD];
#pragma unroll
        for (int o = 0; o < HD; ++o) acc[o] = 0.f;

        float* attn_row = out_attn + ((((size_t)b * NH + h) * NC + i) * NC);
        for (int j = 0; j < NC; ++j) {
            float x = s1 + s2p[j];
            float e = x > 0.f ? x : 0.2f * x;
            float p = expf(e - m) * inv;
            attn_row[j] = p;
            const float* whj = &sm_Wh[j * GD + h * HD];
#pragma unroll
            for (int o = 0; o < HD; ++o)
                acc[o] += p * whj[o];
        }

        // elu + scatter into n_prime (reuse sm_nodes; readers are past barrier)
        float* np_row = &sm_nodes[i * GD + h * HD];
#pragma unroll
        for (int o = 0; o < HD; ++o) {
            float v = acc[o];
            np_row[o] = v > 0.f ? v : expm1f(v);
        }
    }
    __syncthreads();

    // ---- mean over nodes
    if (tid < GD) {
        float s = 0.f;
        for (int c = 0; c < NC; ++c) s += sm_nodes[c * GD + tid];
        sm_mean[tid] = s * (1.0f / NC);
    }
    __syncthreads();

    // ---- readout: g[i] = relu(mean . Wr[i][:] + br[i])
    if (tid < IN_DIM) {
        float acc = br[tid];
#pragma unroll 4
        for (int g = 0; g < GD; ++g)
            acc += sm_mean[g] * Wr[tid * GD + g];
        out_g[(size_t)b * IN_DIM + tid] = fmaxf(acc, 0.f);
    }
}

extern "C" void kernel_launch(void* const* d_in, const int* in_sizes, int n_in,
                              void* d_out, int out_size, void* d_ws, size_t ws_size,
                              hipStream_t stream) {
    const float* H       = (const float*)d_in[0];
    const float* W_embed = (const float*)d_in[1];
    const float* b_embed = (const float*)d_in[2];
    const float* Wh_w    = (const float*)d_in[3];
    const float* a_w     = (const float*)d_in[4];
    const float* Wr      = (const float*)d_in[5];
    const float* br      = (const float*)d_in[6];
    float* out = (float*)d_out;
    float* part = (float*)d_ws;

    const size_t need4 = (size_t)TSPLIT * NB * HID * sizeof(float);  // 8 MB
    const int ts = (ws_size >= need4) ? TSPLIT : 1;

    dim3 g1(HID / 4 / 256, NB, ts);
    pool_kernel<<<g1, dim3(256), 0, stream>>>(H, part, ts);
    gat_kernel<<<dim3(NB), dim3(1024), 0, stream>>>(part, W_embed, b_embed, Wh_w,
                                                    a_w, Wr, br, out,
                                                    out + NB * IN_DIM, ts);
}

// Round 3
// 216.616 us; speedup vs baseline: 1.1415x; 1.0733x over previous
//
#include <hip/hip_runtime.h>
#include <math.h>

#define NB 64
#define NT 512
#define HID 8192
#define NC 64
#define NH 4
#define HD 16
#define GD 64
#define IN_DIM 128
#define TSPLIT 4

// ---------------------------------------------------------------------------
// Kernel 1: temporal partial-sum pooling.
// H [B, T, HID] -> part[ts][b][HID] = sum over t in segment ts.
// ---------------------------------------------------------------------------
__global__ __launch_bounds__(256) void pool_kernel(const float* __restrict__ H,
                                                   float* __restrict__ part,
                                                   int ts_count) {
    const int b = blockIdx.y;
    const int ts = blockIdx.z;
    const int idx4 = blockIdx.x * 256 + threadIdx.x;   // 0..HID/4-1
    const int rows = NT / ts_count;
    const float4* src = reinterpret_cast<const float4*>(H + (size_t)b * NT * HID) +
                        (size_t)(ts * rows) * (HID / 4) + idx4;
    float4 acc = make_float4(0.f, 0.f, 0.f, 0.f);
#pragma unroll 8
    for (int t = 0; t < rows; ++t) {
        float4 v = src[(size_t)t * (HID / 4)];
        acc.x += v.x; acc.y += v.y; acc.z += v.z; acc.w += v.w;
    }
    reinterpret_cast<float4*>(part + ((size_t)ts * NB + b) * HID)[idx4] = acc;
}

// ---------------------------------------------------------------------------
// Kernel 2a: fold partials -> node_inputs, embed GEMM, Wh GEMM, s1/s2.
// grid (NB, NC/16), 256 threads. Block (b, ct) owns node rows ct*16..ct*16+15.
// ---------------------------------------------------------------------------
__global__ __launch_bounds__(256) void embed_kernel(
    const float* __restrict__ part,      // [TS, B, HID]
    const float* __restrict__ W_embed,   // [GD, IN_DIM]
    const float* __restrict__ b_embed,   // [GD]
    const float* __restrict__ Wh_w,      // [NH*HD, GD]
    const float* __restrict__ a_w,       // [NH, 2*HD]
    float* __restrict__ Wh_out,          // [B, C, GD]
    float* __restrict__ s1_out,          // [B, NH, C]
    float* __restrict__ s2_out,          // [B, NH, C]
    int ts_count)
{
    __shared__ float sm_We[IN_DIM * GD];   // transposed [f][g]  32KB
    __shared__ float sm_Ww[GD * GD];       // transposed [g][ho] 16KB
    __shared__ float sm_ni[16 * IN_DIM];   // 8KB
    __shared__ float sm_nodes[16 * GD];    // 4KB
    __shared__ float sm_Wh[16 * GD];       // 4KB

    const int tid = threadIdx.x;
    const int b = blockIdx.x;
    const int ct = blockIdx.y;

    for (int idx = tid; idx < IN_DIM * GD; idx += 256) {
        int g = idx >> 7, f = idx & 127;          // W_embed[g][f]
        sm_We[f * GD + g] = W_embed[idx];
    }
    for (int idx = tid; idx < GD * GD; idx += 256) {
        int ho = idx >> 6, g = idx & 63;          // Wh_w[ho][g]
        sm_Ww[g * GD + ho] = Wh_w[idx];
    }
    for (int idx = tid; idx < 16 * IN_DIM; idx += 256) {
        float s = 0.f;
        for (int ts = 0; ts < ts_count; ++ts)
            s += part[((size_t)ts * NB + b) * HID + ct * (16 * IN_DIM) + idx];
        sm_ni[idx] = s * (1.0f / NT);
    }
    __syncthreads();

    // nodes[c][g4..g4+3]: c = tid>>4 (broadcast ni), g4 = (tid&15)*4 (b128)
    {
        const int c = tid >> 4, g4 = (tid & 15) * 4;
        float4 acc = *reinterpret_cast<const float4*>(&b_embed[g4]);
#pragma unroll 8
        for (int f = 0; f < IN_DIM; ++f) {
            float n = sm_ni[c * IN_DIM + f];
            float4 w = *reinterpret_cast<const float4*>(&sm_We[f * GD + g4]);
            acc.x += n * w.x; acc.y += n * w.y; acc.z += n * w.z; acc.w += n * w.w;
        }
        *reinterpret_cast<float4*>(&sm_nodes[c * GD + g4]) = acc;
    }
    __syncthreads();

    // Wh[c][o4..o4+3]
    {
        const int c = tid >> 4, o4 = (tid & 15) * 4;
        float4 acc = make_float4(0.f, 0.f, 0.f, 0.f);
#pragma unroll 8
        for (int g = 0; g < GD; ++g) {
            float n = sm_nodes[c * GD + g];
            float4 w = *reinterpret_cast<const float4*>(&sm_Ww[g * GD + o4]);
            acc.x += n * w.x; acc.y += n * w.y; acc.z += n * w.z; acc.w += n * w.w;
        }
        *reinterpret_cast<float4*>(&sm_Wh[c * GD + o4]) = acc;
        *reinterpret_cast<float4*>(
            &Wh_out[((size_t)b * NC + ct * 16 + c) * GD + o4]) = acc;
    }
    __syncthreads();

    // s1/s2: threads 0..63 -> (c = tid>>2, h = tid&3)
    if (tid < 64) {
        const int c = tid >> 2, h = tid & 3;
        float a1 = 0.f, a2 = 0.f;
#pragma unroll
        for (int o = 0; o < HD; ++o) {
            float w = sm_Wh[c * GD + h * HD + o];
            a1 += w * a_w[h * 2 * HD + o];
            a2 += w * a_w[h * 2 * HD + HD + o];
        }
        s1_out[((size_t)b * NH + h) * NC + ct * 16 + c] = a1;
        s2_out[((size_t)b * NH + h) * NC + ct * 16 + c] = a2;
    }
}

// ---------------------------------------------------------------------------
// Kernel 2b: softmax attention + PV + elu + node-mean columns.
// grid (NB, NH), 256 threads.
// ---------------------------------------------------------------------------
__global__ __launch_bounds__(256) void attn_kernel(
    const float* __restrict__ Wh_in,     // [B, C, GD]
    const float* __restrict__ s1_in,     // [B, NH, C]
    const float* __restrict__ s2_in,     // [B, NH, C]
    float* __restrict__ out_attn,        // [B, NH, C, C]
    float* __restrict__ mean_out)        // [B, GD]
{
    __shared__ float sm_Wh[NC * HD];     // [j][o]  4KB
    __shared__ float sm_s1[NC], sm_s2[NC], sm_m[NC], sm_inv[NC];
    __shared__ float sm_ho[NC * HD];     // head_out, 4KB

    const int tid = threadIdx.x;
    const int b = blockIdx.x, h = blockIdx.y;

    {   // stage Wh column block [c][h*16..h*16+16): 64 rows x 4 float4
        const int c = tid >> 2, p = tid & 3;
        *reinterpret_cast<float4*>(&sm_Wh[c * HD + p * 4]) =
            *reinterpret_cast<const float4*>(
                &Wh_in[((size_t)b * NC + c) * GD + h * HD + p * 4]);
    }
    if (tid < NC) sm_s1[tid] = s1_in[((size_t)b * NH + h) * NC + tid];
    else if (tid < 2 * NC) sm_s2[tid - NC] = s2_in[((size_t)b * NH + h) * NC + tid - NC];
    __syncthreads();

    // row stats
    if (tid < NC) {
        const float s1 = sm_s1[tid];
        float m = -1e30f;
        for (int j = 0; j < NC; ++j) {
            float x = s1 + sm_s2[j];
            float e = x > 0.f ? x : 0.2f * x;
            m = fmaxf(m, e);
        }
        float sum = 0.f;
        for (int j = 0; j < NC; ++j) {
            float x = s1 + sm_s2[j];
            float e = x > 0.f ? x : 0.2f * x;
            sum += __expf(e - m);
        }
        sm_m[tid] = m;
        sm_inv[tid] = 1.0f / sum;
    }
    __syncthreads();

    // attn writes, coalesced float4
    float4* attn_b = reinterpret_cast<float4*>(out_attn + ((size_t)b * NH + h) * NC * NC);
    for (int idx4 = tid; idx4 < NC * NC / 4; idx4 += 256) {
        const int i = idx4 >> 4, j = (idx4 & 15) * 4;
        const float s1 = sm_s1[i], m = sm_m[i], inv = sm_inv[i];
        float4 p;
        {
            float x = s1 + sm_s2[j + 0]; float e = x > 0.f ? x : 0.2f * x;
            p.x = __expf(e - m) * inv;
        }
        {
            float x = s1 + sm_s2[j + 1]; float e = x > 0.f ? x : 0.2f * x;
            p.y = __expf(e - m) * inv;
        }
        {
            float x = s1 + sm_s2[j + 2]; float e = x > 0.f ? x : 0.2f * x;
            p.z = __expf(e - m) * inv;
        }
        {
            float x = s1 + sm_s2[j + 3]; float e = x > 0.f ? x : 0.2f * x;
            p.w = __expf(e - m) * inv;
        }
        attn_b[idx4] = p;
    }

    // PV: thread (i = tid&63, og = tid>>6) owns 4 outputs
    {
        const int i = tid & 63, og = tid >> 6;
        const float s1 = sm_s1[i], m = sm_m[i], inv = sm_inv[i];
        float a0 = 0.f, a1 = 0.f, a2 = 0.f, a3 = 0.f;
        for (int j = 0; j < NC; ++j) {
            float x = s1 + sm_s2[j];
            float e = x > 0.f ? x : 0.2f * x;
            float p = __expf(e - m) * inv;
            const float* w = &sm_Wh[j * HD + og * 4];   // wave-uniform: broadcast
            a0 += p * w[0]; a1 += p * w[1]; a2 += p * w[2]; a3 += p * w[3];
        }
        float* ho = &sm_ho[i * HD + og * 4];
        ho[0] = a0 > 0.f ? a0 : expm1f(a0);
        ho[1] = a1 > 0.f ? a1 : expm1f(a1);
        ho[2] = a2 > 0.f ? a2 : expm1f(a2);
        ho[3] = a3 > 0.f ? a3 : expm1f(a3);
    }
    __syncthreads();

    // node-mean for this block's 16 output columns
    if (tid < HD) {
        float s = 0.f;
        for (int i = 0; i < NC; ++i) s += sm_ho[i * HD + tid];
        mean_out[(size_t)b * GD + h * HD + tid] = s * (1.0f / NC);
    }
}

// ---------------------------------------------------------------------------
// Kernel 2c: readout. grid (NB), 128 threads.
// ---------------------------------------------------------------------------
__global__ __launch_bounds__(128) void readout_kernel(
    const float* __restrict__ mean_in,   // [B, GD]
    const float* __restrict__ Wr,        // [IN_DIM, GD]
    const float* __restrict__ br,        // [IN_DIM]
    float* __restrict__ out_g)           // [B, IN_DIM]
{
    __shared__ float sm_mean[GD];
    __shared__ float sm_WrT[GD * (IN_DIM + 1)];   // padded transposed

    const int tid = threadIdx.x;
    const int b = blockIdx.x;

    if (tid < GD) sm_mean[tid] = mean_in[(size_t)b * GD + tid];
    for (int idx = tid; idx < IN_DIM * GD; idx += 128) {
        int i = idx >> 6, g = idx & 63;           // Wr[i][g]
        sm_WrT[g * (IN_DIM + 1) + i] = Wr[idx];
    }
    __syncthreads();

    float acc = br[tid];
#pragma unroll 8
    for (int g = 0; g < GD; ++g)
        acc += sm_mean[g] * sm_WrT[g * (IN_DIM + 1) + tid];
    out_g[(size_t)b * IN_DIM + tid] = fmaxf(acc, 0.f);
}

extern "C" void kernel_launch(void* const* d_in, const int* in_sizes, int n_in,
                              void* d_out, int out_size, void* d_ws, size_t ws_size,
                              hipStream_t stream) {
    const float* H       = (const float*)d_in[0];
    const float* W_embed = (const float*)d_in[1];
    const float* b_embed = (const float*)d_in[2];
    const float* Wh_w    = (const float*)d_in[3];
    const float* a_w     = (const float*)d_in[4];
    const float* Wr      = (const float*)d_in[5];
    const float* br      = (const float*)d_in[6];
    float* out = (float*)d_out;
    float* out_attn = out + NB * IN_DIM;

    // workspace layout
    const size_t need4 = ((size_t)TSPLIT * NB * HID + NB * NC * GD +
                          2 * NB * NH * NC + NB * GD) * sizeof(float);
    const int ts = (ws_size >= need4) ? TSPLIT : 1;

    float* part   = (float*)d_ws;                         // [ts, B, HID]
    float* Wh_ws  = part + (size_t)ts * NB * HID;         // [B, C, GD]
    float* s1_ws  = Wh_ws + (size_t)NB * NC * GD;         // [B, NH, C]
    float* s2_ws  = s1_ws + (size_t)NB * NH * NC;         // [B, NH, C]
    float* mean_ws = s2_ws + (size_t)NB * NH * NC;        // [B, GD]

    dim3 g1(HID / 4 / 256, NB, ts);
    pool_kernel<<<g1, dim3(256), 0, stream>>>(H, part, ts);
    embed_kernel<<<dim3(NB, NC / 16), dim3(256), 0, stream>>>(
        part, W_embed, b_embed, Wh_w, a_w, Wh_ws, s1_ws, s2_ws, ts);
    attn_kernel<<<dim3(NB, NH), dim3(256), 0, stream>>>(
        Wh_ws, s1_ws, s2_ws, out_attn, mean_ws);
    readout_kernel<<<dim3(NB), dim3(128), 0, stream>>>(mean_ws, Wr, br, out);
}

// Round 5
// 193.867 us; speedup vs baseline: 1.2755x; 1.1173x over previous
//
#include <hip/hip_runtime.h>
#include <math.h>

#define NB 64
#define NT 512
#define HID 8192
#define NC 64
#define NH 4
#define HD 16
#define GD 64
#define IN_DIM 128
#define TSPLIT 4

typedef float f32x4 __attribute__((ext_vector_type(4)));

// ---------------------------------------------------------------------------
// Kernel 1: temporal partial-sum pooling.
// H [B, T, HID] -> part[ts][b][HID] = sum over t in segment ts.
// Two independent accumulator chains + nontemporal loads for max MLP.
// ---------------------------------------------------------------------------
__global__ __launch_bounds__(256) void pool_kernel(const float* __restrict__ H,
                                                   float* __restrict__ part,
                                                   int ts_count) {
    const int b = blockIdx.y;
    const int ts = blockIdx.z;
    const int idx4 = blockIdx.x * 256 + threadIdx.x;   // 0..HID/4-1
    const int rows = NT / ts_count;                     // even for ts in {1,4}
    const f32x4* src = reinterpret_cast<const f32x4*>(H + (size_t)b * NT * HID) +
                       (size_t)(ts * rows) * (HID / 4) + idx4;
    f32x4 a0 = (f32x4)0.f;
    f32x4 a1 = (f32x4)0.f;
#pragma unroll 8
    for (int t = 0; t < rows; t += 2) {
        f32x4 v0 = __builtin_nontemporal_load(&src[(size_t)t * (HID / 4)]);
        f32x4 v1 = __builtin_nontemporal_load(&src[(size_t)(t + 1) * (HID / 4)]);
        a0 += v0;
        a1 += v1;
    }
    a0 += a1;
    reinterpret_cast<f32x4*>(part + ((size_t)ts * NB + b) * HID)[idx4] = a0;
}

// ---------------------------------------------------------------------------
// Kernel 2a: fold partials -> node_inputs, embed GEMM, Wh GEMM, s1/s2.
// grid (NB, NC/16), 256 threads. Block (b, ct) owns node rows ct*16..ct*16+15.
// ---------------------------------------------------------------------------
__global__ __launch_bounds__(256) void embed_kernel(
    const float* __restrict__ part,      // [TS, B, HID]
    const float* __restrict__ W_embed,   // [GD, IN_DIM]
    const float* __restrict__ b_embed,   // [GD]
    const float* __restrict__ Wh_w,      // [NH*HD, GD]
    const float* __restrict__ a_w,       // [NH, 2*HD]
    float* __restrict__ Wh_out,          // [B, C, GD]
    float* __restrict__ s1_out,          // [B, NH, C]
    float* __restrict__ s2_out,          // [B, NH, C]
    int ts_count)
{
    __shared__ float sm_We[IN_DIM * GD];   // transposed [f][g]  32KB
    __shared__ float sm_Ww[GD * GD];       // transposed [g][ho] 16KB
    __shared__ float sm_ni[16 * IN_DIM];   // 8KB
    __shared__ float sm_nodes[16 * GD];    // 4KB
    __shared__ float sm_Wh[16 * GD];       // 4KB

    const int tid = threadIdx.x;
    const int b = blockIdx.x;
    const int ct = blockIdx.y;

    for (int idx = tid; idx < IN_DIM * GD; idx += 256) {
        int g = idx >> 7, f = idx & 127;          // W_embed[g][f]
        sm_We[f * GD + g] = W_embed[idx];
    }
    for (int idx = tid; idx < GD * GD; idx += 256) {
        int ho = idx >> 6, g = idx & 63;          // Wh_w[ho][g]
        sm_Ww[g * GD + ho] = Wh_w[idx];
    }
    // fold partial sums, float4-vectorized: 16*IN_DIM = 2048 floats = 512 float4
    for (int idx4 = tid; idx4 < 16 * IN_DIM / 4; idx4 += 256) {
        f32x4 s = (f32x4)0.f;
        for (int ts = 0; ts < ts_count; ++ts) {
            f32x4 v = reinterpret_cast<const f32x4*>(
                &part[((size_t)ts * NB + b) * HID + ct * (16 * IN_DIM)])[idx4];
            s += v;
        }
        reinterpret_cast<f32x4*>(sm_ni)[idx4] = s * (1.0f / NT);
    }
    __syncthreads();

    // nodes[c][g4..g4+3]: c = tid>>4 (broadcast ni), g4 = (tid&15)*4 (b128)
    {
        const int c = tid >> 4, g4 = (tid & 15) * 4;
        f32x4 acc = *reinterpret_cast<const f32x4*>(&b_embed[g4]);
#pragma unroll 8
        for (int f = 0; f < IN_DIM; ++f) {
            float n = sm_ni[c * IN_DIM + f];
            f32x4 w = *reinterpret_cast<const f32x4*>(&sm_We[f * GD + g4]);
            acc += n * w;
        }
        *reinterpret_cast<f32x4*>(&sm_nodes[c * GD + g4]) = acc;
    }
    __syncthreads();

    // Wh[c][o4..o4+3]
    {
        const int c = tid >> 4, o4 = (tid & 15) * 4;
        f32x4 acc = (f32x4)0.f;
#pragma unroll 8
        for (int g = 0; g < GD; ++g) {
            float n = sm_nodes[c * GD + g];
            f32x4 w = *reinterpret_cast<const f32x4*>(&sm_Ww[g * GD + o4]);
            acc += n * w;
        }
        *reinterpret_cast<f32x4*>(&sm_Wh[c * GD + o4]) = acc;
        *reinterpret_cast<f32x4*>(
            &Wh_out[((size_t)b * NC + ct * 16 + c) * GD + o4]) = acc;
    }
    __syncthreads();

    // s1/s2: threads 0..63 -> (c = tid>>2, h = tid&3)
    if (tid < 64) {
        const int c = tid >> 2, h = tid & 3;
        float a1 = 0.f, a2 = 0.f;
#pragma unroll
        for (int o = 0; o < HD; ++o) {
            float w = sm_Wh[c * GD + h * HD + o];
            a1 += w * a_w[h * 2 * HD + o];
            a2 += w * a_w[h * 2 * HD + HD + o];
        }
        s1_out[((size_t)b * NH + h) * NC + ct * 16 + c] = a1;
        s2_out[((size_t)b * NH + h) * NC + ct * 16 + c] = a2;
    }
}

// ---------------------------------------------------------------------------
// Kernel 2b: softmax attention + PV + elu + node-mean columns.
// grid (NB, NH), 256 threads.
// ---------------------------------------------------------------------------
__global__ __launch_bounds__(256) void attn_kernel(
    const float* __restrict__ Wh_in,     // [B, C, GD]
    const float* __restrict__ s1_in,     // [B, NH, C]
    const float* __restrict__ s2_in,     // [B, NH, C]
    float* __restrict__ out_attn,        // [B, NH, C, C]
    float* __restrict__ mean_out)        // [B, GD]
{
    __shared__ float sm_Wh[NC * HD];     // [j][o]  4KB
    __shared__ float sm_s1[NC], sm_s2[NC], sm_m[NC], sm_inv[NC];
    __shared__ float sm_ho[NC * HD];     // head_out, 4KB

    const int tid = threadIdx.x;
    const int b = blockIdx.x, h = blockIdx.y;

    {   // stage Wh column block [c][h*16..h*16+16): 64 rows x 4 float4
        const int c = tid >> 2, p = tid & 3;
        *reinterpret_cast<f32x4*>(&sm_Wh[c * HD + p * 4]) =
            *reinterpret_cast<const f32x4*>(
                &Wh_in[((size_t)b * NC + c) * GD + h * HD + p * 4]);
    }
    if (tid < NC) sm_s1[tid] = s1_in[((size_t)b * NH + h) * NC + tid];
    else if (tid < 2 * NC) sm_s2[tid - NC] = s2_in[((size_t)b * NH + h) * NC + tid - NC];
    __syncthreads();

    // row stats
    if (tid < NC) {
        const float s1 = sm_s1[tid];
        float m = -1e30f;
        for (int j = 0; j < NC; ++j) {
            float x = s1 + sm_s2[j];
            float e = x > 0.f ? x : 0.2f * x;
            m = fmaxf(m, e);
        }
        float sum = 0.f;
        for (int j = 0; j < NC; ++j) {
            float x = s1 + sm_s2[j];
            float e = x > 0.f ? x : 0.2f * x;
            sum += __expf(e - m);
        }
        sm_m[tid] = m;
        sm_inv[tid] = 1.0f / sum;
    }
    __syncthreads();

    // attn writes, coalesced float4
    f32x4* attn_b = reinterpret_cast<f32x4*>(out_attn + ((size_t)b * NH + h) * NC * NC);
    for (int idx4 = tid; idx4 < NC * NC / 4; idx4 += 256) {
        const int i = idx4 >> 4, j = (idx4 & 15) * 4;
        const float s1 = sm_s1[i], m = sm_m[i], inv = sm_inv[i];
        f32x4 p;
        {
            float x = s1 + sm_s2[j + 0]; float e = x > 0.f ? x : 0.2f * x;
            p.x = __expf(e - m) * inv;
        }
        {
            float x = s1 + sm_s2[j + 1]; float e = x > 0.f ? x : 0.2f * x;
            p.y = __expf(e - m) * inv;
        }
        {
            float x = s1 + sm_s2[j + 2]; float e = x > 0.f ? x : 0.2f * x;
            p.z = __expf(e - m) * inv;
        }
        {
            float x = s1 + sm_s2[j + 3]; float e = x > 0.f ? x : 0.2f * x;
            p.w = __expf(e - m) * inv;
        }
        attn_b[idx4] = p;
    }

    // PV: thread (i = tid&63, og = tid>>6) owns 4 outputs
    {
        const int i = tid & 63, og = tid >> 6;
        const float s1 = sm_s1[i], m = sm_m[i], inv = sm_inv[i];
        float a0 = 0.f, a1 = 0.f, a2 = 0.f, a3 = 0.f;
        for (int j = 0; j < NC; ++j) {
            float x = s1 + sm_s2[j];
            float e = x > 0.f ? x : 0.2f * x;
            float p = __expf(e - m) * inv;
            const float* w = &sm_Wh[j * HD + og * 4];   // 4 distinct addrs/wave: broadcast
            a0 += p * w[0]; a1 += p * w[1]; a2 += p * w[2]; a3 += p * w[3];
        }
        float* ho = &sm_ho[i * HD + og * 4];
        ho[0] = a0 > 0.f ? a0 : expm1f(a0);
        ho[1] = a1 > 0.f ? a1 : expm1f(a1);
        ho[2] = a2 > 0.f ? a2 : expm1f(a2);
        ho[3] = a3 > 0.f ? a3 : expm1f(a3);
    }
    __syncthreads();

    // node-mean for this block's 16 output columns
    if (tid < HD) {
        float s = 0.f;
        for (int i = 0; i < NC; ++i) s += sm_ho[i * HD + tid];
        mean_out[(size_t)b * GD + h * HD + tid] = s * (1.0f / NC);
    }
}

// ---------------------------------------------------------------------------
// Kernel 2c: readout. grid (NB), 128 threads.
// ---------------------------------------------------------------------------
__global__ __launch_bounds__(128) void readout_kernel(
    const float* __restrict__ mean_in,   // [B, GD]
    const float* __restrict__ Wr,        // [IN_DIM, GD]
    const float* __restrict__ br,        // [IN_DIM]
    float* __restrict__ out_g)           // [B, IN_DIM]
{
    __shared__ float sm_mean[GD];
    __shared__ float sm_WrT[GD * (IN_DIM + 1)];   // padded transposed

    const int tid = threadIdx.x;
    const int b = blockIdx.x;

    if (tid < GD) sm_mean[tid] = mean_in[(size_t)b * GD + tid];
    for (int idx = tid; idx < IN_DIM * GD; idx += 128) {
        int i = idx >> 6, g = idx & 63;           // Wr[i][g]
        sm_WrT[g * (IN_DIM + 1) + i] = Wr[idx];
    }
    __syncthreads();

    float acc = br[tid];
#pragma unroll 8
    for (int g = 0; g < GD; ++g)
        acc += sm_mean[g] * sm_WrT[g * (IN_DIM + 1) + tid];
    out_g[(size_t)b * IN_DIM + tid] = fmaxf(acc, 0.f);
}

extern "C" void kernel_launch(void* const* d_in, const int* in_sizes, int n_in,
                              void* d_out, int out_size, void* d_ws, size_t ws_size,
                              hipStream_t stream) {
    const float* H       = (const float*)d_in[0];
    const float* W_embed = (const float*)d_in[1];
    const float* b_embed = (const float*)d_in[2];
    const float* Wh_w    = (const float*)d_in[3];
    const float* a_w     = (const float*)d_in[4];
    const float* Wr      = (const float*)d_in[5];
    const float* br      = (const float*)d_in[6];
    float* out = (float*)d_out;
    float* out_attn = out + NB * IN_DIM;

    // workspace layout
    const size_t need4 = ((size_t)TSPLIT * NB * HID + NB * NC * GD +
                          2 * NB * NH * NC + NB * GD) * sizeof(float);
    const int ts = (ws_size >= need4) ? TSPLIT : 1;

    float* part   = (float*)d_ws;                         // [ts, B, HID]
    float* Wh_ws  = part + (size_t)ts * NB * HID;         // [B, C, GD]
    float* s1_ws  = Wh_ws + (size_t)NB * NC * GD;         // [B, NH, C]
    float* s2_ws  = s1_ws + (size_t)NB * NH * NC;         // [B, NH, C]
    float* mean_ws = s2_ws + (size_t)NB * NH * NC;        // [B, GD]

    dim3 g1(HID / 4 / 256, NB, ts);
    pool_kernel<<<g1, dim3(256), 0, stream>>>(H, part, ts);
    embed_kernel<<<dim3(NB, NC / 16), dim3(256), 0, stream>>>(
        part, W_embed, b_embed, Wh_w, a_w, Wh_ws, s1_ws, s2_ws, ts);
    attn_kernel<<<dim3(NB, NH), dim3(256), 0, stream>>>(
        Wh_ws, s1_ws, s2_ws, out_attn, mean_ws);
    readout_kernel<<<dim3(NB), dim3(128), 0, stream>>>(mean_ws, Wr, br, out);
}